// Round 6
// baseline (382.748 us; speedup 1.0000x reference)
//
#include <hip/hip_runtime.h>
#include <hip/hip_bf16.h>

#define BH   16
#define SEQ  2048
#define DH   64
#define TQ   16
#define VST  40      // Vt row stride in f16 (80B: 16B-aligned, bank-spread via XOR)
#define EST  40      // Eb row stride in f16

typedef _Float16 f16;
using f32x4 = __attribute__((ext_vector_type(4))) float;
using f16x8 = __attribute__((ext_vector_type(8))) _Float16;
using f16x4 = __attribute__((ext_vector_type(4))) _Float16;

// ============================ Kernel A ============================
// Wave-autonomous flash: each wave owns 16 q-rows x 1024-k half. NO barriers
// in the k-loop: all LDS traffic (V-transpose, P-relayout) is same-wave, so
// compiler-inserted lgkmcnt ordering is sufficient. One __syncthreads at the
// end combines the two k-half partials (lsum, oacc).
__global__ __launch_bounds__(256, 3)
void mha_pass_a(const float* __restrict__ key,
                const float* __restrict__ value,
                const float* __restrict__ query,
                const int*   __restrict__ mask,
                const float* __restrict__ qmask,
                float* __restrict__ out_res,
                float* __restrict__ out_attn)
{
  // Per-wave private arenas (indexed by wave id -> no cross-wave hazards).
  __shared__ f16  Vt[4][DH + 1][VST];   // V^T [d][k], XOR-swizzled; +1 row for XOR overflow
  __shared__ f16  Eb[4][TQ][EST];       // P relayout bounce [q][k_local]
  __shared__ float comb[2][64][18];     // k-half-1 partials: 16 oacc + 1 lsum

  const int tid  = threadIdx.x;
  const int lane = tid & 63;
  const int w    = tid >> 6;
  const int lr   = lane & 15;
  const int g    = lane >> 4;

  // XCD-chunked swizzle (1024 blocks, 128/XCD -> 2 bh per XCD, K/V L2-resident)
  int B = blockIdx.x;
  B = (B & 7) * 128 + (B >> 3);
  const int bh = B >> 6;                    // 64 blocks per bh
  const int qt = (B & 63) * 2 + (w & 1);    // q-tile 0..127
  const int q0 = qt * TQ;
  const int kh = w >> 1;                    // k-half 0/1
  const int kb0 = kh * (SEQ / 2);

  const size_t mbase = (size_t)bh * SEQ * SEQ;
  const float* kb_ = key   + (size_t)bh * SEQ * DH;
  const float* vb_ = value + (size_t)bh * SEQ * DH;
  const int*   mrow = mask + mbase + (size_t)(q0 + lr) * SEQ;

  char* vtb = (char*)&Vt[w][0][0];
  char* ebb = (char*)&Eb[w][0][0];

  // ---- Q fragments direct to registers: Q[q=lr][ch*32 + g*8 .. +8] ----
  f16x8 qf0, qf1;
  {
    const float* qrow = query + ((size_t)(bh * SEQ + q0 + lr)) * DH;
    f32x4 a0 = *(const f32x4*)(qrow + g * 8);
    f32x4 a1 = *(const f32x4*)(qrow + g * 8 + 4);
    f32x4 a2 = *(const f32x4*)(qrow + 32 + g * 8);
    f32x4 a3 = *(const f32x4*)(qrow + 32 + g * 8 + 4);
    #pragma unroll
    for (int e = 0; e < 4; ++e) {
      qf0[e] = (f16)a0[e]; qf0[4 + e] = (f16)a1[e];
      qf1[e] = (f16)a2[e]; qf1[4 + e] = (f16)a3[e];
    }
  }

  // per-lane pointer into the f16 strip (second half of this q-row's f32 row)
  f16* aph = (f16*)(out_attn + mbase + (size_t)(q0 + lr) * SEQ) + 2048;

  // V staging coords: lane covers rows k0+r4..r4+3, cols c8..c8+7
  const int r4 = (lane & 7) * 4;
  const int c8 = (lane >> 3) * 8;

  f32x4 oacc[4];
  #pragma unroll
  for (int d = 0; d < 4; ++d) oacc[d] = (f32x4){0.f, 0.f, 0.f, 0.f};
  float lsum = 0.f;

  for (int st = 0; st < SEQ / 2 / 32; ++st) {
    const int k0 = kb0 + st * 32;

    // ---- load V 32x64 (f32, coalesced-ish) ----
    f32x4 va[4][2];
    {
      const float* vs = vb_ + (size_t)(k0 + r4) * DH + c8;
      #pragma unroll
      for (int j = 0; j < 4; ++j) {
        va[j][0] = *(const f32x4*)(vs + j * DH);
        va[j][1] = *(const f32x4*)(vs + j * DH + 4);
      }
    }
    // ---- transpose to Vt[d][k]: 8x ds_write_b64 (4 consecutive k packed) ----
    #pragma unroll
    for (int d8 = 0; d8 < 8; ++d8) {
      const int d = c8 + d8;
      f16x4 t = { (f16)va[0][d8 >> 2][d8 & 3], (f16)va[1][d8 >> 2][d8 & 3],
                  (f16)va[2][d8 >> 2][d8 & 3], (f16)va[3][d8 >> 2][d8 & 3] };
      int byte = d * (VST * 2) + r4 * 2;
      byte ^= ((d >> 4) & 1) << 6;          // bank-spread XOR (both sides)
      *(f16x4*)(vtb + byte) = t;
    }

    // ---- K fragments + masks ----
    f16x8 kf[2][2];
    int4  mm[2];
    #pragma unroll
    for (int blk = 0; blk < 2; ++blk) {
      const float* ks = kb_ + (size_t)(k0 + blk * 16 + lr) * DH + g * 8;
      f32x4 b0 = *(const f32x4*)(ks);
      f32x4 b1 = *(const f32x4*)(ks + 4);
      f32x4 b2 = *(const f32x4*)(ks + 32);
      f32x4 b3 = *(const f32x4*)(ks + 36);
      #pragma unroll
      for (int e = 0; e < 4; ++e) {
        kf[blk][0][e] = (f16)b0[e]; kf[blk][0][4 + e] = (f16)b1[e];
        kf[blk][1][e] = (f16)b2[e]; kf[blk][1][4 + e] = (f16)b3[e];
      }
      mm[blk] = *(const int4*)(mrow + k0 + blk * 16 + g * 4);
    }

    // ---- QK^T swapped: D[k_loc = blk*16+g*4+i][q = lr] ----
    #pragma unroll
    for (int blk = 0; blk < 2; ++blk) {
      f32x4 s = {0.f, 0.f, 0.f, 0.f};
      s = __builtin_amdgcn_mfma_f32_16x16x32_f16(kf[blk][0], qf0, s, 0, 0, 0);
      s = __builtin_amdgcn_mfma_f32_16x16x32_f16(kf[blk][1], qf1, s, 0, 0, 0);
      const int mk[4] = { mm[blk].x, mm[blk].y, mm[blk].z, mm[blk].w };
      f16x4 pb;
      #pragma unroll
      for (int i = 0; i < 4; ++i) {
        const float p = mk[i] ? 0.f : __expf(s[i] * 0.125f);
        lsum += p;
        pb[i] = (f16)p;
      }
      *(f16x4*)(ebb + lr * (EST * 2) + blk * 32 + g * 8) = pb;  // [q=lr][k_loc]
    }

    // ---- P relayout read: lane gets p[q=lr][k = g*8..+8] ----
    f16x8 pfrag = *(const f16x8*)(ebb + lr * (EST * 2) + g * 16);

    // ---- unnormalized P' -> global f16 strip (16B, 4 lanes/row contiguous) ----
    *(f16x8*)(aph + k0 + g * 8) = pfrag;

    // ---- PV swapped: O^T = V^T . P^T ; lane gets O[q=lr][d=dblk*16+g*4+i] ----
    #pragma unroll
    for (int dblk = 0; dblk < 4; ++dblk) {
      int byte = (dblk * 16 + lr) * (VST * 2) + g * 16;
      byte ^= (dblk & 1) << 6;              // same XOR as write side
      f16x8 vf = *(const f16x8*)(vtb + byte);
      oacc[dblk] = __builtin_amdgcn_mfma_f32_16x16x32_f16(vf, pfrag, oacc[dblk], 0, 0, 0);
    }
  }

  // ---- reduce lsum across g-groups (q=lr everywhere) ----
  lsum += __shfl_xor(lsum, 16);
  lsum += __shfl_xor(lsum, 32);

  // ---- combine the two k-halves (the only barrier in the kernel) ----
  if (kh == 1) {
    #pragma unroll
    for (int d = 0; d < 4; ++d) {
      #pragma unroll
      for (int i = 0; i < 4; ++i) comb[w & 1][lane][d * 4 + i] = oacc[d][i];
    }
    comb[w & 1][lane][16] = lsum;
  }
  __syncthreads();
  if (kh == 0) {
    #pragma unroll
    for (int d = 0; d < 4; ++d) {
      #pragma unroll
      for (int i = 0; i < 4; ++i) oacc[d][i] += comb[w & 1][lane][d * 4 + i];
    }
    lsum += comb[w & 1][lane][16];

    const float rsc = qmask[bh * SEQ + q0 + lr] / fmaxf(lsum, 1e-37f);
    float* orow = out_res + ((size_t)(bh * SEQ + q0 + lr)) * DH;
    #pragma unroll
    for (int d = 0; d < 4; ++d) {
      f32x4 o = { oacc[d][0] * rsc, oacc[d][1] * rsc,
                  oacc[d][2] * rsc, oacc[d][3] * rsc };
      *(f32x4*)(orow + d * 16 + g * 4) = o;
    }
  }
}

// ============================ Kernel B ============================
// One wave per row: read 4KB f16 strip, l = sum, write 8KB f32 row scaled.
// The l-reduction orders all loads before any store -> in-place expansion safe.
__global__ __launch_bounds__(256)
void mha_pass_b(const float* __restrict__ qmask,
                float* __restrict__ out_attn)
{
  const int lane = threadIdx.x & 63;
  const int wv   = threadIdx.x >> 6;
  const int row  = blockIdx.x * 4 + wv;

  float* rowp = out_attn + (size_t)row * SEQ;
  const f16x8* src = (const f16x8*)((const f16*)rowp + 2048 + lane * 32);

  f16x8 v0 = src[0], v1 = src[1], v2 = src[2], v3 = src[3];

  float f[32];
  #pragma unroll
  for (int j = 0; j < 8; ++j) {
    f[j]      = (float)v0[j];
    f[8 + j]  = (float)v1[j];
    f[16 + j] = (float)v2[j];
    f[24 + j] = (float)v3[j];
  }
  float lsum = 0.f;
  #pragma unroll
  for (int j = 0; j < 32; ++j) lsum += f[j];
  #pragma unroll
  for (int off = 1; off < 64; off <<= 1) lsum += __shfl_xor(lsum, off);

  const float scale = qmask[row] / fmaxf(lsum, 1e-37f);

  float4* dst = (float4*)(rowp + lane * 32);
  #pragma unroll
  for (int m = 0; m < 8; ++m) {
    float4 o = { f[m * 4 + 0] * scale, f[m * 4 + 1] * scale,
                 f[m * 4 + 2] * scale, f[m * 4 + 3] * scale };
    dst[m] = o;
  }
}

extern "C" void kernel_launch(void* const* d_in, const int* in_sizes, int n_in,
                              void* d_out, int out_size, void* d_ws, size_t ws_size,
                              hipStream_t stream) {
  const float* key   = (const float*)d_in[0];
  const float* value = (const float*)d_in[1];
  const float* query = (const float*)d_in[2];
  const int*   mask  = (const int*)d_in[3];
  const float* qmask = (const float*)d_in[4];

  float* out_res  = (float*)d_out;                       // [16,2048,64]
  float* out_attn = out_res + (size_t)BH * SEQ * DH;     // [16,2048,2048]

  mha_pass_a<<<dim3(1024), dim3(256), 0, stream>>>(
      key, value, query, mask, qmask, out_res, out_attn);

  mha_pass_b<<<dim3(BH * SEQ / 4), dim3(256), 0, stream>>>(qmask, out_attn);
}

// Round 7
// 298.396 us; speedup vs baseline: 1.2827x; 1.2827x over previous
//
#include <hip/hip_runtime.h>
#include <hip/hip_bf16.h>

#define BH   16
#define SEQ  2048
#define DH   64
#define TQ   16
#define TK   64
#define NT   (SEQ / TK)   // 32 k-tiles
#define PST  72           // Ps row stride in f16 (144 B)

typedef _Float16 f16;
typedef unsigned int u32;
using f32x4 = __attribute__((ext_vector_type(4))) float;
using f16x8 = __attribute__((ext_vector_type(8))) _Float16;
using f16x4 = __attribute__((ext_vector_type(4))) _Float16;

#define AS1 __attribute__((address_space(1)))
#define AS3 __attribute__((address_space(3)))

// async global->LDS DMA, 16B per lane: dest = uniform base + lane*16,
// source = per-lane address. Tracked by vmcnt; __syncthreads drains it.
static __device__ __forceinline__ void gload16(void* lds, const void* g) {
  __builtin_amdgcn_global_load_lds((const AS1 u32*)g, (AS3 u32*)lds, 16, 0, 0);
}

// Scratch-in-output: f16 tiles live in the FIRST half (4 KB) of out_attn rows.
// Tile (bh,t,which) = 8 KB = two 4 KB chunks in rows 2*cid and 2*cid+1.
// Strips (written by pass_a) live in SECOND halves -> disjoint. pass_b later
// overwrites every row, so scratch never leaks to the validated output.
static __device__ __forceinline__ size_t scr_byte(int bh, int t, int which,
                                                  int byte_in_tile) {
  const int cid = (bh * NT + t) * 2 + which;
  return (size_t)(cid * 2 + (byte_in_tile >> 12)) * 8192 + (byte_in_tile & 4095);
}

// ============================ prep kernel ============================
// K -> f16 row-major tiles; V -> f16 TRANSPOSED tiles [d][k]; both stored
// with the T2 XOR-swizzle (byte ^= (row&7)<<4 on 16B chunks) pre-applied so
// pass_a can global_load_lds them linearly and read conflict-free.
__global__ __launch_bounds__(256)
void mha_prep(const float* __restrict__ key,
              const float* __restrict__ value,
              float* __restrict__ out_attn)
{
  __shared__ float Vl[64][68];
  const int tid = threadIdx.x;
  const int bt  = blockIdx.x;          // 0..BH*NT-1
  const int bh  = bt >> 5, t = bt & 31;
  const int k0  = t * TK;
  char* oa = (char*)out_attn;

  const int r  = tid >> 2;             // 0..63
  const int cs = (tid & 3) * 16;       // 0,16,32,48

  { // ---- K tile ----
    const float* src = key + ((size_t)(bh * SEQ + k0 + r)) * DH + cs;
    f32x4 a0 = *(const f32x4*)(src);
    f32x4 a1 = *(const f32x4*)(src + 4);
    f32x4 a2 = *(const f32x4*)(src + 8);
    f32x4 a3 = *(const f32x4*)(src + 12);
    f16x8 h0, h1;
    #pragma unroll
    for (int e = 0; e < 4; ++e) {
      h0[e] = (f16)a0[e]; h0[4 + e] = (f16)a1[e];
      h1[e] = (f16)a2[e]; h1[4 + e] = (f16)a3[e];
    }
    const int swz = (r & 7) << 4;
    *(f16x8*)(oa + scr_byte(bh, t, 0, r * 128 + ((cs * 2) ^ swz)))      = h0;
    *(f16x8*)(oa + scr_byte(bh, t, 0, r * 128 + ((cs * 2 + 16) ^ swz))) = h1;
  }
  { // ---- V stage to LDS (f32) ----
    const float* src = value + ((size_t)(bh * SEQ + k0 + r)) * DH + cs;
    *(f32x4*)&Vl[r][cs]      = *(const f32x4*)(src);
    *(f32x4*)&Vl[r][cs + 4]  = *(const f32x4*)(src + 4);
    *(f32x4*)&Vl[r][cs + 8]  = *(const f32x4*)(src + 8);
    *(f32x4*)&Vl[r][cs + 12] = *(const f32x4*)(src + 12);
  }
  __syncthreads();
  { // ---- V^T tile ----
    const int d = tid >> 2, ks = (tid & 3) * 16;
    f16x8 h0, h1;
    #pragma unroll
    for (int j = 0; j < 8; ++j) h0[j] = (f16)Vl[ks + j][d];
    #pragma unroll
    for (int j = 0; j < 8; ++j) h1[j] = (f16)Vl[ks + 8 + j][d];
    const int swz = (d & 7) << 4;
    *(f16x8*)(oa + scr_byte(bh, t, 1, d * 128 + ((ks * 2) ^ swz)))      = h0;
    *(f16x8*)(oa + scr_byte(bh, t, 1, d * 128 + ((ks * 2 + 16) ^ swz))) = h1;
  }
}

// ============================ pass A ============================
// 4 waves share one 16-q tile; wave w owns k-sub/d-sub w*16. Per step:
// QK -> issue K-DMA(t+1) -> mask/exp/P -> bar -> PV -> issue V-DMA(t+1).
// One barrier per step; its vmcnt drain completes the DMAs.
__global__ __launch_bounds__(256, 4)
void mha_pass_a(const float* __restrict__ query,
                const int*   __restrict__ mask,
                const float* __restrict__ qmask,
                const float* __restrict__ out_attn_c,
                float* __restrict__ out_res,
                float* __restrict__ out_attn)
{
  __shared__ char KsB[2][8192];
  __shared__ char VsB[2][8192];
  __shared__ f16  Ps[2][TQ][PST];
  __shared__ float lred[4][TQ];
  __shared__ float rsc[TQ];

  const int tid  = threadIdx.x;
  const int lane = tid & 63;
  const int w    = tid >> 6;
  const int lr   = lane & 15;
  const int g    = lane >> 4;

  // XCD-chunked swizzle: 2048 blocks, 256 per XCD
  int flat = (blockIdx.x & 7) * 256 + (blockIdx.x >> 3);
  const int bh = flat >> 7;
  const int q0 = (flat & 127) * TQ;
  const size_t mbase = (size_t)bh * SEQ * SEQ;
  const int* mrow = mask + mbase + (size_t)(q0 + lr) * SEQ + w * 16 + g * 4;
  const char* oa = (const char*)out_attn_c;

  // ---- Q fragments (f32 -> f16, registers) ----
  f16x8 qf0, qf1;
  {
    const float* qrow = query + ((size_t)(bh * SEQ + q0 + lr)) * DH;
    f32x4 a0 = *(const f32x4*)(qrow + g * 8);
    f32x4 a1 = *(const f32x4*)(qrow + g * 8 + 4);
    f32x4 a2 = *(const f32x4*)(qrow + 32 + g * 8);
    f32x4 a3 = *(const f32x4*)(qrow + 32 + g * 8 + 4);
    #pragma unroll
    for (int e = 0; e < 4; ++e) {
      qf0[e] = (f16)a0[e]; qf0[4 + e] = (f16)a1[e];
      qf1[e] = (f16)a2[e]; qf1[4 + e] = (f16)a3[e];
    }
  }

  f16* aph = (f16*)(out_attn + mbase + (size_t)(q0 + lr) * SEQ) + 2048;

  // ---- prologue: DMA tile 0, mask 0 ----
  #pragma unroll
  for (int u = 0; u < 2; ++u) {
    const int j = w * 2 + u;
    gload16(KsB[0] + j * 1024, oa + scr_byte(bh, 0, 0, j * 1024) + lane * 16);
    gload16(VsB[0] + j * 1024, oa + scr_byte(bh, 0, 1, j * 1024) + lane * 16);
  }
  int4 mreg = *(const int4*)(mrow);
  __syncthreads();   // drains DMA for tile 0

  f32x4 oacc = {0.f, 0.f, 0.f, 0.f};
  float lsum = 0.f;
  const int row16 = w * 16 + lr;          // k-row (QK) and d-row (PV)
  const int swz   = (row16 & 7) << 4;

  for (int t = 0; t < NT; ++t) {
    const int cur = t & 1, nxt = cur ^ 1;

    // ---- QK^T on KsB[cur] (swapped: D[k_loc=g*4+i][q=lr]) ----
    f16x8 kf0 = *(const f16x8*)(KsB[cur] + row16 * 128 + ((16 * g) ^ swz));
    f16x8 kf1 = *(const f16x8*)(KsB[cur] + row16 * 128 + ((64 + 16 * g) ^ swz));
    f32x4 s = {0.f, 0.f, 0.f, 0.f};
    s = __builtin_amdgcn_mfma_f32_16x16x32_f16(kf0, qf0, s, 0, 0, 0);
    s = __builtin_amdgcn_mfma_f32_16x16x32_f16(kf1, qf1, s, 0, 0, 0);

    // ---- issue K-DMA for t+1 (fire-and-forget) ----
    if (t + 1 < NT) {
      #pragma unroll
      for (int u = 0; u < 2; ++u) {
        const int j = w * 2 + u;
        gload16(KsB[nxt] + j * 1024,
                oa + scr_byte(bh, t + 1, 0, j * 1024) + lane * 16);
      }
    }

    // ---- mask + exp -> strip + Ps ----
    const int4 mc = mreg;
    if (t + 1 < NT) mreg = *(const int4*)(mrow + (t + 1) * TK);
    const float p0 = mc.x ? 0.f : __expf(s[0] * 0.125f);
    const float p1 = mc.y ? 0.f : __expf(s[1] * 0.125f);
    const float p2 = mc.z ? 0.f : __expf(s[2] * 0.125f);
    const float p3 = mc.w ? 0.f : __expf(s[3] * 0.125f);
    lsum += (p0 + p1) + (p2 + p3);
    f16x4 pk = { (f16)p0, (f16)p1, (f16)p2, (f16)p3 };
    *(f16x4*)(aph + t * TK + w * 16 + g * 4) = pk;
    *(f16x4*)&Ps[cur][lr][w * 16 + g * 4] = pk;

    __syncthreads();   // Ps ready; K/V DMA drained; prior reads retired

    // ---- PV on VsB[cur]: O[q=lr][d=w*16+g*4+i] ----
    f16x8 vf0 = *(const f16x8*)(VsB[cur] + row16 * 128 + ((16 * g) ^ swz));
    f16x8 vf1 = *(const f16x8*)(VsB[cur] + row16 * 128 + ((64 + 16 * g) ^ swz));
    f16x8 pf0 = *(const f16x8*)&Ps[cur][lr][g * 8];
    f16x8 pf1 = *(const f16x8*)&Ps[cur][lr][32 + g * 8];
    oacc = __builtin_amdgcn_mfma_f32_16x16x32_f16(vf0, pf0, oacc, 0, 0, 0);
    oacc = __builtin_amdgcn_mfma_f32_16x16x32_f16(vf1, pf1, oacc, 0, 0, 0);

    // ---- issue V-DMA for t+1 (targets VsB[nxt]: prior reads ordered by bar) ----
    if (t + 1 < NT) {
      #pragma unroll
      for (int u = 0; u < 2; ++u) {
        const int j = w * 2 + u;
        gload16(VsB[nxt] + j * 1024,
                oa + scr_byte(bh, t + 1, 1, j * 1024) + lane * 16);
      }
    }
  }

  // ---- l per q-row ----
  {
    float ssum = lsum;
    ssum += __shfl_xor(ssum, 16);
    ssum += __shfl_xor(ssum, 32);
    if (lane < 16) lred[w][lane] = ssum;
  }
  __syncthreads();
  if (tid < TQ) {
    const float l = lred[0][tid] + lred[1][tid] + lred[2][tid] + lred[3][tid];
    rsc[tid] = qmask[bh * SEQ + q0 + tid] / fmaxf(l, 1e-37f);
  }
  __syncthreads();

  // ---- result write (f32x4: d = w*16 + g*4 .. +4) ----
  {
    const float rs = rsc[lr];
    f32x4 o = { oacc[0] * rs, oacc[1] * rs, oacc[2] * rs, oacc[3] * rs };
    *(f32x4*)(out_res + ((size_t)(bh * SEQ + q0 + lr)) * DH + w * 16 + g * 4) = o;
  }
}

// ============================ pass B ============================
// One wave per row: read 4KB f16 strip, l = sum, write 8KB f32 row scaled.
// The reduction orders all loads before any store -> in-place expansion safe.
__global__ __launch_bounds__(256)
void mha_pass_b(const float* __restrict__ qmask,
                float* __restrict__ out_attn)
{
  const int lane = threadIdx.x & 63;
  const int wv   = threadIdx.x >> 6;
  const int row  = blockIdx.x * 4 + wv;

  float* rowp = out_attn + (size_t)row * SEQ;
  const f16x8* src = (const f16x8*)((const f16*)rowp + 2048 + lane * 32);

  f16x8 v0 = src[0], v1 = src[1], v2 = src[2], v3 = src[3];

  float f[32];
  #pragma unroll
  for (int j = 0; j < 8; ++j) {
    f[j]      = (float)v0[j];
    f[8 + j]  = (float)v1[j];
    f[16 + j] = (float)v2[j];
    f[24 + j] = (float)v3[j];
  }
  float lsum = 0.f;
  #pragma unroll
  for (int j = 0; j < 32; ++j) lsum += f[j];
  #pragma unroll
  for (int off = 1; off < 64; off <<= 1) lsum += __shfl_xor(lsum, off);

  const float scale = qmask[row] / fmaxf(lsum, 1e-37f);

  float4* dst = (float4*)(rowp + lane * 32);
  #pragma unroll
  for (int m = 0; m < 8; ++m) {
    float4 o = { f[m * 4 + 0] * scale, f[m * 4 + 1] * scale,
                 f[m * 4 + 2] * scale, f[m * 4 + 3] * scale };
    dst[m] = o;
  }
}

extern "C" void kernel_launch(void* const* d_in, const int* in_sizes, int n_in,
                              void* d_out, int out_size, void* d_ws, size_t ws_size,
                              hipStream_t stream) {
  const float* key   = (const float*)d_in[0];
  const float* value = (const float*)d_in[1];
  const float* query = (const float*)d_in[2];
  const int*   mask  = (const int*)d_in[3];
  const float* qmask = (const float*)d_in[4];

  float* out_res  = (float*)d_out;                       // [16,2048,64]
  float* out_attn = out_res + (size_t)BH * SEQ * DH;     // [16,2048,2048]

  mha_prep<<<dim3(BH * NT), dim3(256), 0, stream>>>(key, value, out_attn);

  mha_pass_a<<<dim3(2048), dim3(256), 0, stream>>>(
      query, mask, qmask, out_attn, out_res, out_attn);

  mha_pass_b<<<dim3(BH * SEQ / 4), dim3(256), 0, stream>>>(qmask, out_attn);
}